// Round 5
// baseline (5787.086 us; speedup 1.0000x reference)
//
#include <hip/hip_runtime.h>
#include <hip/hip_bf16.h>
#include <stdint.h>

#define BATCH 64
#define SEQ   512
#define INDIM 1024
#define HDIM  1024
#define NGRP  4      // batch groups of 16 rows
#define BPG   64     // blocks per group (each owns 16 hidden cols)

typedef short bf16x8 __attribute__((ext_vector_type(8)));
typedef float f32x4  __attribute__((ext_vector_type(4)));
typedef unsigned short u16;
typedef unsigned int   u32;
typedef u32 u32x4 __attribute__((ext_vector_type(4)));

static __device__ __forceinline__ u16 f2bf(float x) {
  unsigned int u = __float_as_uint(x);
  u += 0x7fffu + ((u >> 16) & 1u);
  return (u16)(u >> 16);
}
static __device__ __forceinline__ float bf2f(u16 b) {
  return __uint_as_float(((unsigned int)b) << 16);
}

// coherent (device-scope, L1/L2-bypass) scalar load for flag polling
static __device__ __forceinline__ int coh_ld_i32(const int* p) {
  int v;
  asm volatile("global_load_dword %0, %1, off sc0 sc1\n\t"
               "s_waitcnt vmcnt(0)"
               : "=&v"(v) : "v"(p) : "memory");
  return v;
}

static __device__ __forceinline__ void split8(float4 a, float4 b, bf16x8& hi, bf16x8& lo) {
  union { u16 u[8]; bf16x8 v; } H, L;
  float f[8] = {a.x, a.y, a.z, a.w, b.x, b.y, b.z, b.w};
#pragma unroll
  for (int i = 0; i < 8; ++i) {
    u16 h = f2bf(f[i]);
    H.u[i] = h;
    L.u[i] = f2bf(f[i] - bf2f(h));
  }
  hi = H.v; lo = L.v;
}

// ---- init: zero flags, pack h0 into fragment-major hi|lo layout ----
// hpack slot: [(g*32 + k32)*64 + kg*16 + r] -> 16 u16 (8 hi | 8 lo)
// holds h[g*16 + r][k32*32 + kg*8 + j]
__global__ void init_kernel(const float* __restrict__ h0, u16* __restrict__ hbuf0,
                            int* __restrict__ flags) {
  int i = blockIdx.x * blockDim.x + threadIdx.x;
  if (i < NGRP * BPG) flags[i] = 0;
  if (i < BATCH * HDIM) {
    int b = i >> 10, k = i & 1023;
    int g = b >> 4, r = b & 15;
    int k32 = k >> 5, kg = (k >> 3) & 3, j = k & 7;
    float x = h0[i];
    u16 h = f2bf(x);
    size_t u = ((size_t)(g * 32 + k32) * 64 + kg * 16 + r) * 16 + j;
    hbuf0[u] = h;
    hbuf0[u + 8] = f2bf(x - bf2f(h));
  }
}

// ---- fused persistent scan: h_t = relu(x_t Wih^T + b + h_{t-1} Whh^T) ----
// 256 blocks x 512 thr. Block b: group g=b&3 (16 batch rows), cols c=b>>2 (16).
// 8 waves K-split 128 each; W slices (hi/lo, both mats) resident in LDS.
__global__ __launch_bounds__(512, 1) void rnn_fused(
    const float* __restrict__ X, const float* __restrict__ Wih,
    const float* __restrict__ Whh, const float* __restrict__ bih,
    const float* __restrict__ bhh, float* __restrict__ out,
    u16* hbuf0, u16* hbuf1, int* flags) {
  __shared__ u16 WihH[32][64][8], WihL[32][64][8];
  __shared__ u16 WhhH[32][64][8], WhhL[32][64][8];
  __shared__ float red[2][8][16][17];   // double-buffered, padded (bank-conflict fix)
  __shared__ float biasS[16];

  const int blk = (int)blockIdx.x;
  const int g = blk & 3;
  const int c = blk >> 2;
  const int m0 = g * 16;
  const int n0 = c * 16;
  const int tid = (int)threadIdx.x;
  const int wv = tid >> 6, lane = tid & 63;
  const int r = lane & 15, kg = lane >> 4;

  // ---- one-time: stage W slices into LDS, fragment-major, split hi/lo ----
  for (int mat = 0; mat < 2; ++mat) {
    const float* W = mat ? Whh : Wih;
    u16 (*Lh)[64][8] = mat ? WhhH : WihH;
    u16 (*Ll)[64][8] = mat ? WhhL : WihL;
    for (int it = 0; it < 8; ++it) {
      int f4 = it * 512 + tid;            // float4 index in 16x1024 slice
      int row = f4 >> 8;                  // 0..15
      int k0 = (f4 & 255) * 4;            // 0..1020
      float4 v = *(const float4*)(W + (size_t)(n0 + row) * INDIM + k0);
      int k32 = k0 >> 5, kgg = (k0 >> 3) & 3, j = k0 & 7;
      int ln = kgg * 16 + row;
      u16* ph = &Lh[k32][ln][j];
      u16* pl = &Ll[k32][ln][j];
      u16 h;
      h = f2bf(v.x); ph[0] = h; pl[0] = f2bf(v.x - bf2f(h));
      h = f2bf(v.y); ph[1] = h; pl[1] = f2bf(v.y - bf2f(h));
      h = f2bf(v.z); ph[2] = h; pl[2] = f2bf(v.z - bf2f(h));
      h = f2bf(v.w); ph[3] = h; pl[3] = f2bf(v.w - bf2f(h));
    }
  }
  if (tid < 16) biasS[tid] = bih[n0 + tid] + bhh[n0 + tid];
  __syncthreads();

  // x prefetch + pre-split for step 0
  const size_t xbase = ((size_t)(m0 + r) * SEQ) * INDIM + (size_t)(wv * 128 + kg * 8);
  float4 xf[8];
  bf16x8 xh[4], xl[4];
#pragma unroll
  for (int i = 0; i < 4; ++i) {
    xf[2 * i]     = *(const float4*)(X + xbase + i * 32);
    xf[2 * i + 1] = *(const float4*)(X + xbase + i * 32 + 4);
  }
#pragma unroll
  for (int i = 0; i < 4; ++i) split8(xf[2 * i], xf[2 * i + 1], xh[i], xl[i]);

  const size_t gofs = (size_t)g << 16;  // group offset in hpack (bytes)
  int* const myflag = flags + g * BPG;

  for (int t = 0; t < SEQ; ++t) {
    const int p = t & 1;
    const char* hc = (const char*)(p ? hbuf1 : hbuf0) + gofs;
    char*       hn = (char*)      (p ? hbuf0 : hbuf1) + gofs;

    // (a) all-wave parallel poll: lane l watches flag of group-block l
    if (t > 0) {
      const int* fp = myflag + lane;
      while (true) {
        int v = coh_ld_i32(fp);
        if (__all(v >= t)) break;
        __builtin_amdgcn_s_sleep(1);
      }
    }

    // (b) coherent-load this wave's h A-fragments (8 x 16B, pipelined)
    u32x4 hh[4], hl[4];
    const char* a0 = hc + (size_t)((wv * 4 + 0) * 64 + lane) * 32;
    const char* a1 = hc + (size_t)((wv * 4 + 2) * 64 + lane) * 32;
    asm volatile(
        "global_load_dwordx4 %0, %8, off sc0 sc1\n\t"
        "global_load_dwordx4 %1, %8, off offset:16 sc0 sc1\n\t"
        "global_load_dwordx4 %2, %8, off offset:2048 sc0 sc1\n\t"
        "global_load_dwordx4 %3, %8, off offset:2064 sc0 sc1\n\t"
        "global_load_dwordx4 %4, %9, off sc0 sc1\n\t"
        "global_load_dwordx4 %5, %9, off offset:16 sc0 sc1\n\t"
        "global_load_dwordx4 %6, %9, off offset:2048 sc0 sc1\n\t"
        "global_load_dwordx4 %7, %9, off offset:2064 sc0 sc1"
        : "=&v"(hh[0]), "=&v"(hl[0]), "=&v"(hh[1]), "=&v"(hl[1]),
          "=&v"(hh[2]), "=&v"(hl[2]), "=&v"(hh[3]), "=&v"(hl[3])
        : "v"(a0), "v"(a1)
        : "memory");
    asm volatile("s_waitcnt vmcnt(0)"
        : "+v"(hh[0]), "+v"(hl[0]), "+v"(hh[1]), "+v"(hl[1]),
          "+v"(hh[2]), "+v"(hl[2]), "+v"(hh[3]), "+v"(hl[3]));

    f32x4 acc = {0.f, 0.f, 0.f, 0.f};
#pragma unroll
    for (int i = 0; i < 4; ++i) {
      int k32 = wv * 4 + i;
      bf16x8 ah = __builtin_bit_cast(bf16x8, hh[i]);
      bf16x8 al = __builtin_bit_cast(bf16x8, hl[i]);
      bf16x8 bh = *(const bf16x8*)&WhhH[k32][lane][0];
      bf16x8 bl = *(const bf16x8*)&WhhL[k32][lane][0];
      acc = __builtin_amdgcn_mfma_f32_16x16x32_bf16(ah, bh, acc, 0, 0, 0);
      acc = __builtin_amdgcn_mfma_f32_16x16x32_bf16(ah, bl, acc, 0, 0, 0);
      acc = __builtin_amdgcn_mfma_f32_16x16x32_bf16(al, bh, acc, 0, 0, 0);
      bf16x8 wh = *(const bf16x8*)&WihH[k32][lane][0];
      bf16x8 wl = *(const bf16x8*)&WihL[k32][lane][0];
      acc = __builtin_amdgcn_mfma_f32_16x16x32_bf16(xh[i], wh, acc, 0, 0, 0);
      acc = __builtin_amdgcn_mfma_f32_16x16x32_bf16(xh[i], wl, acc, 0, 0, 0);
      acc = __builtin_amdgcn_mfma_f32_16x16x32_bf16(xl[i], wh, acc, 0, 0, 0);
    }

    // prefetch x(t+1) — loads fly during reduction/epilogue
    if (t + 1 < SEQ) {
      const float* xp = X + xbase + (size_t)(t + 1) * INDIM;
#pragma unroll
      for (int i = 0; i < 4; ++i) {
        xf[2 * i]     = *(const float4*)(xp + i * 32);
        xf[2 * i + 1] = *(const float4*)(xp + i * 32 + 4);
      }
    }

    // (c) cross-wave K-reduction. D layout: n = lane&15, m = kg*4+q
#pragma unroll
    for (int q = 0; q < 4; ++q) red[p][wv][kg * 4 + q][r] = acc[q];
    __syncthreads();

    if (tid < 32) {
      // wave 0: pack h(t+1), store coherently, set flag
      int rr = tid >> 1, o = tid & 1;   // row, col-octet
      union { u16 u[8]; u32x4 q; } HH, LL;
#pragma unroll
      for (int j = 0; j < 8; ++j) {
        float s = biasS[o * 8 + j];
#pragma unroll
        for (int w = 0; w < 8; ++w) s += red[p][w][rr][o * 8 + j];
        s = s > 0.f ? s : 0.f;
        u16 h = f2bf(s);
        HH.u[j] = h;
        LL.u[j] = f2bf(s - bf2f(h));
      }
      int kk = n0 + o * 8;
      int k32 = kk >> 5, kgg = (kk >> 3) & 3;
      char* hp = hn + (size_t)(k32 * 64 + kgg * 16 + rr) * 32;
      asm volatile(
          "global_store_dwordx4 %0, %1, off sc0 sc1\n\t"
          "global_store_dwordx4 %0, %2, off offset:16 sc0 sc1\n\t"
          "s_waitcnt vmcnt(0)"
          :: "v"(hp), "v"(HH.q), "v"(LL.q)
          : "memory");
      if (tid == 0) {
        int* fp = myflag + c;
        int tv = t + 1;
        asm volatile("global_store_dword %0, %1, off sc0 sc1"
                     :: "v"(fp), "v"(tv) : "memory");
      }
    } else if (tid >= 64 && tid < 320) {
      // waves 1-4: compute + store outputs (write-only)
      int idx = tid - 64;
      int m = idx >> 4, n = idx & 15;
      float s = biasS[n];
#pragma unroll
      for (int w = 0; w < 8; ++w) s += red[p][w][m][n];
      s = s > 0.f ? s : 0.f;
      __builtin_nontemporal_store(s, out + ((size_t)(m0 + m) * SEQ + t) * HDIM + n0 + n);
    }

    // pre-split x(t+1) off the critical path
    if (t + 1 < SEQ) {
#pragma unroll
      for (int i = 0; i < 4; ++i) split8(xf[2 * i], xf[2 * i + 1], xh[i], xl[i]);
    }
  }
}

// ---- h_n = outputs[:, SEQ-1, :] ----
__global__ void copy_hn(const float* __restrict__ out, float* __restrict__ hn) {
  int idx = blockIdx.x * blockDim.x + threadIdx.x;
  if (idx < BATCH * HDIM) {
    int b = idx >> 10, j = idx & 1023;
    hn[idx] = out[((size_t)b * SEQ + (SEQ - 1)) * (size_t)HDIM + j];
  }
}

extern "C" void kernel_launch(void* const* d_in, const int* in_sizes, int n_in,
                              void* d_out, int out_size, void* d_ws, size_t ws_size,
                              hipStream_t stream) {
  const float* inputs = (const float*)d_in[0];
  const float* h0     = (const float*)d_in[1];
  const float* w_ih   = (const float*)d_in[2];
  const float* w_hh   = (const float*)d_in[3];
  const float* b_ih   = (const float*)d_in[4];
  const float* b_hh   = (const float*)d_in[5];

  float* outBase = (float*)d_out;
  float* hnBase  = outBase + (size_t)BATCH * SEQ * HDIM;

  // ws: hpack ping-pong (2 x 256 KB) + flags (1 KB)
  u16* hbuf0 = (u16*)d_ws;
  u16* hbuf1 = hbuf0 + (size_t)NGRP * 32 * 64 * 16;
  int* flags = (int*)(hbuf1 + (size_t)NGRP * 32 * 64 * 16);

  init_kernel<<<256, 256, 0, stream>>>(h0, hbuf0, flags);

  const float* xa = inputs;
  const float* wia = w_ih;
  const float* wha = w_hh;
  const float* bia = b_ih;
  const float* bha = b_hh;
  float* oa = outBase;
  u16 *hb0 = hbuf0, *hb1 = hbuf1;
  int* fa = flags;
  void* args[9] = {&xa, &wia, &wha, &bia, &bha, &oa, &hb0, &hb1, &fa};
  hipLaunchCooperativeKernel((const void*)rnn_fused, dim3(NGRP * BPG), dim3(512), args, 0, stream);

  copy_hn<<<256, 256, 0, stream>>>(outBase, hnBase);
}

// Round 6
// 2117.868 us; speedup vs baseline: 2.7325x; 2.7325x over previous
//
#include <hip/hip_runtime.h>
#include <hip/hip_bf16.h>
#include <stdint.h>

#define BATCH 64
#define SEQ   512
#define INDIM 1024
#define HDIM  1024
#define NGRP  4      // batch groups of 16 rows
#define BPG   64     // blocks per group (each owns 16 hidden cols)
#define FPAD  16     // flag padding: 16 ints = 64 B, one cache line per flag

typedef short bf16x8 __attribute__((ext_vector_type(8)));
typedef float f32x4  __attribute__((ext_vector_type(4)));
typedef unsigned short u16;
typedef unsigned int   u32;
typedef u32 u32x2 __attribute__((ext_vector_type(2)));
typedef u32 u32x4 __attribute__((ext_vector_type(4)));

static __device__ __forceinline__ u16 f2bf(float x) {
  unsigned int u = __float_as_uint(x);
  u += 0x7fffu + ((u >> 16) & 1u);
  return (u16)(u >> 16);
}
static __device__ __forceinline__ float bf2f(u16 b) {
  return __uint_as_float(((unsigned int)b) << 16);
}

// coherent (device-scope, L2-bypass) scalar load for flag polling
static __device__ __forceinline__ int coh_ld_i32(const int* p) {
  int v;
  asm volatile("global_load_dword %0, %1, off sc0 sc1\n\t"
               "s_waitcnt vmcnt(0)"
               : "=&v"(v) : "v"(p) : "memory");
  return v;
}

static __device__ __forceinline__ void split8(float4 a, float4 b, bf16x8& hi, bf16x8& lo) {
  union { u16 u[8]; bf16x8 v; } H, L;
  float f[8] = {a.x, a.y, a.z, a.w, b.x, b.y, b.z, b.w};
#pragma unroll
  for (int i = 0; i < 8; ++i) {
    u16 h = f2bf(f[i]);
    H.u[i] = h;
    L.u[i] = f2bf(f[i] - bf2f(h));
  }
  hi = H.v; lo = L.v;
}

// ---- init: zero flags, pack h0 into fragment-major hi|lo layout ----
// hpack slot: [(g*32 + k32)*64 + kg*16 + r] -> 16 u16 (8 hi | 8 lo)
// holds h[g*16 + r][k32*32 + kg*8 + j]
__global__ void init_kernel(const float* __restrict__ h0, u16* __restrict__ hbuf0,
                            int* __restrict__ flags) {
  int i = blockIdx.x * blockDim.x + threadIdx.x;
  if (i < NGRP * BPG * FPAD) flags[i] = 0;
  if (i < BATCH * HDIM) {
    int b = i >> 10, k = i & 1023;
    int g = b >> 4, r = b & 15;
    int k32 = k >> 5, kg = (k >> 3) & 3, j = k & 7;
    float x = h0[i];
    u16 h = f2bf(x);
    size_t u = ((size_t)(g * 32 + k32) * 64 + kg * 16 + r) * 16 + j;
    hbuf0[u] = h;
    hbuf0[u + 8] = f2bf(x - bf2f(h));
  }
}

// ---- fused persistent scan: h_t = relu(x_t Wih^T + b + h_{t-1} Whh^T) ----
// 256 blocks x 512 thr. Block b: group g=b&3 (16 batch rows), cols c=b>>2 (16).
// 8 waves K-split 128 each; W slices (hi/lo, both mats) resident in LDS.
__global__ __launch_bounds__(512, 1) void rnn_fused(
    const float* __restrict__ X, const float* __restrict__ Wih,
    const float* __restrict__ Whh, const float* __restrict__ bih,
    const float* __restrict__ bhh, float* __restrict__ out,
    u16* hbuf0, u16* hbuf1, int* flags) {
  __shared__ u16 WihH[32][64][8], WihL[32][64][8];
  __shared__ u16 WhhH[32][64][8], WhhL[32][64][8];
  __shared__ __align__(16) float red[2][8][16][20];  // dbuf; 20-stride: 16B-aligned rows, 2-way banks
  __shared__ __align__(16) float biasS[16];

  const int blk = (int)blockIdx.x;
  const int g = blk & 3;
  const int c = blk >> 2;
  const int m0 = g * 16;
  const int n0 = c * 16;
  const int tid = (int)threadIdx.x;
  const int wv = tid >> 6, lane = tid & 63;
  const int r = lane & 15, kg = lane >> 4;

  // ---- one-time: stage W slices into LDS, fragment-major, split hi/lo ----
  for (int mat = 0; mat < 2; ++mat) {
    const float* W = mat ? Whh : Wih;
    u16 (*Lh)[64][8] = mat ? WhhH : WihH;
    u16 (*Ll)[64][8] = mat ? WhhL : WihL;
    for (int it = 0; it < 8; ++it) {
      int f4 = it * 512 + tid;            // float4 index in 16x1024 slice
      int row = f4 >> 8;                  // 0..15
      int k0 = (f4 & 255) * 4;            // 0..1020
      float4 v = *(const float4*)(W + (size_t)(n0 + row) * INDIM + k0);
      int k32 = k0 >> 5, kgg = (k0 >> 3) & 3, j = k0 & 7;
      int ln = kgg * 16 + row;
      u16* ph = &Lh[k32][ln][j];
      u16* pl = &Ll[k32][ln][j];
      u16 h;
      h = f2bf(v.x); ph[0] = h; pl[0] = f2bf(v.x - bf2f(h));
      h = f2bf(v.y); ph[1] = h; pl[1] = f2bf(v.y - bf2f(h));
      h = f2bf(v.z); ph[2] = h; pl[2] = f2bf(v.z - bf2f(h));
      h = f2bf(v.w); ph[3] = h; pl[3] = f2bf(v.w - bf2f(h));
    }
  }
  if (tid < 16) biasS[tid] = bih[n0 + tid] + bhh[n0 + tid];
  __syncthreads();

  // x prefetch + pre-split for step 0
  const size_t xbase = ((size_t)(m0 + r) * SEQ) * INDIM + (size_t)(wv * 128 + kg * 8);
  float4 xf[8];
  bf16x8 xh[4], xl[4];
#pragma unroll
  for (int i = 0; i < 4; ++i) {
    xf[2 * i]     = *(const float4*)(X + xbase + i * 32);
    xf[2 * i + 1] = *(const float4*)(X + xbase + i * 32 + 4);
  }
#pragma unroll
  for (int i = 0; i < 4; ++i) split8(xf[2 * i], xf[2 * i + 1], xh[i], xl[i]);

  const size_t gofs = (size_t)g << 16;  // group offset in hpack (bytes)
  int* const gflag = flags + g * BPG * FPAD;

  for (int t = 0; t < SEQ; ++t) {
    const int p = t & 1;
    const char* hc = (const char*)(p ? hbuf1 : hbuf0) + gofs;
    char*       hn = (char*)      (p ? hbuf0 : hbuf1) + gofs;

    // (a) wave-0-only parallel poll: lane l watches flag of group-block l
    if (wv == 0 && t > 0) {
      const int* fp = gflag + lane * FPAD;
      int v;
      do { v = coh_ld_i32(fp); } while (!__all(v >= t));
    }
    __syncthreads();   // barrier A: release all waves

    // (b) coherent-load this wave's h A-fragments (8 x 16B, pipelined)
    u32x4 hh[4], hl[4];
    const char* a0 = hc + (size_t)((wv * 4 + 0) * 64 + lane) * 32;
    const char* a1 = hc + (size_t)((wv * 4 + 2) * 64 + lane) * 32;
    asm volatile(
        "global_load_dwordx4 %0, %8, off sc0 sc1\n\t"
        "global_load_dwordx4 %1, %8, off offset:16 sc0 sc1\n\t"
        "global_load_dwordx4 %2, %8, off offset:2048 sc0 sc1\n\t"
        "global_load_dwordx4 %3, %8, off offset:2064 sc0 sc1\n\t"
        "global_load_dwordx4 %4, %9, off sc0 sc1\n\t"
        "global_load_dwordx4 %5, %9, off offset:16 sc0 sc1\n\t"
        "global_load_dwordx4 %6, %9, off offset:2048 sc0 sc1\n\t"
        "global_load_dwordx4 %7, %9, off offset:2064 sc0 sc1"
        : "=&v"(hh[0]), "=&v"(hl[0]), "=&v"(hh[1]), "=&v"(hl[1]),
          "=&v"(hh[2]), "=&v"(hl[2]), "=&v"(hh[3]), "=&v"(hl[3])
        : "v"(a0), "v"(a1)
        : "memory");
    asm volatile("s_waitcnt vmcnt(0)"
        : "+v"(hh[0]), "+v"(hl[0]), "+v"(hh[1]), "+v"(hl[1]),
          "+v"(hh[2]), "+v"(hl[2]), "+v"(hh[3]), "+v"(hl[3]));

    f32x4 acc = {0.f, 0.f, 0.f, 0.f};
#pragma unroll
    for (int i = 0; i < 4; ++i) {
      int k32 = wv * 4 + i;
      bf16x8 ah = __builtin_bit_cast(bf16x8, hh[i]);
      bf16x8 al = __builtin_bit_cast(bf16x8, hl[i]);
      bf16x8 bh = *(const bf16x8*)&WhhH[k32][lane][0];
      bf16x8 bl = *(const bf16x8*)&WhhL[k32][lane][0];
      acc = __builtin_amdgcn_mfma_f32_16x16x32_bf16(ah, bh, acc, 0, 0, 0);
      acc = __builtin_amdgcn_mfma_f32_16x16x32_bf16(ah, bl, acc, 0, 0, 0);
      acc = __builtin_amdgcn_mfma_f32_16x16x32_bf16(al, bh, acc, 0, 0, 0);
      bf16x8 wh = *(const bf16x8*)&WihH[k32][lane][0];
      bf16x8 wl = *(const bf16x8*)&WihL[k32][lane][0];
      acc = __builtin_amdgcn_mfma_f32_16x16x32_bf16(xh[i], wh, acc, 0, 0, 0);
      acc = __builtin_amdgcn_mfma_f32_16x16x32_bf16(xh[i], wl, acc, 0, 0, 0);
      acc = __builtin_amdgcn_mfma_f32_16x16x32_bf16(xl[i], wh, acc, 0, 0, 0);
    }

    // prefetch x(t+1) — loads fly during reduction/epilogue
    if (t + 1 < SEQ) {
      const float* xp = X + xbase + (size_t)(t + 1) * INDIM;
#pragma unroll
      for (int i = 0; i < 4; ++i) {
        xf[2 * i]     = *(const float4*)(xp + i * 32);
        xf[2 * i + 1] = *(const float4*)(xp + i * 32 + 4);
      }
    }

    // (c) cross-wave K-reduction. D layout: n = lane&15, m = kg*4+q
#pragma unroll
    for (int q = 0; q < 4; ++q) red[p][wv][kg * 4 + q][r] = acc[q];
    __syncthreads();   // barrier B

    if (wv == 0) {
      // wave 0 (all 64 lanes): reduce 4 cols each, pack h(t+1), store, set flag
      int rr = lane >> 2, o = lane & 3;       // row 0..15, col-nibble 0..3
      f32x4 s = *(const f32x4*)&biasS[o * 4];
#pragma unroll
      for (int w = 0; w < 8; ++w) s += *(const f32x4*)&red[p][w][rr][o * 4];
#pragma unroll
      for (int j = 0; j < 4; ++j) s[j] = s[j] > 0.f ? s[j] : 0.f;
      union { u16 u[4]; u32x2 d; } HH, LL;
#pragma unroll
      for (int j = 0; j < 4; ++j) {
        u16 h = f2bf(s[j]);
        HH.u[j] = h;
        LL.u[j] = f2bf(s[j] - bf2f(h));
      }
      // global col range: n0 + o*4 .. +3 ; all 16 cols share k32 = n0>>5
      int k32 = n0 >> 5;
      int kgg = ((n0 >> 3) & 3) + (o >> 1);
      char* hp = hn + (size_t)(k32 * 64 + kgg * 16 + rr) * 32 + (o & 1) * 8;
      asm volatile(
          "global_store_dwordx2 %0, %1, off sc0 sc1\n\t"
          "global_store_dwordx2 %0, %2, off offset:16 sc0 sc1\n\t"
          "s_waitcnt vmcnt(0)"
          :: "v"(hp), "v"(HH.d), "v"(LL.d)
          : "memory");
      if (lane == 0) {
        int* fp = gflag + c * FPAD;
        int tv = t + 1;
        asm volatile("global_store_dword %0, %1, off sc0 sc1"
                     :: "v"(fp), "v"(tv) : "memory");
      }
    } else if (wv >= 1 && wv <= 4) {
      // waves 1-4: compute + store outputs (write-only)
      int idx = tid - 64;
      int m = idx >> 4, n = idx & 15;
      float s = biasS[n];
#pragma unroll
      for (int w = 0; w < 8; ++w) s += red[p][w][m][n];
      s = s > 0.f ? s : 0.f;
      __builtin_nontemporal_store(s, out + ((size_t)(m0 + m) * SEQ + t) * HDIM + n0 + n);
    }

    // pre-split x(t+1) off the critical path
    if (t + 1 < SEQ) {
#pragma unroll
      for (int i = 0; i < 4; ++i) split8(xf[2 * i], xf[2 * i + 1], xh[i], xl[i]);
    }
  }
}

// ---- h_n = outputs[:, SEQ-1, :] ----
__global__ void copy_hn(const float* __restrict__ out, float* __restrict__ hn) {
  int idx = blockIdx.x * blockDim.x + threadIdx.x;
  if (idx < BATCH * HDIM) {
    int b = idx >> 10, j = idx & 1023;
    hn[idx] = out[((size_t)b * SEQ + (SEQ - 1)) * (size_t)HDIM + j];
  }
}

extern "C" void kernel_launch(void* const* d_in, const int* in_sizes, int n_in,
                              void* d_out, int out_size, void* d_ws, size_t ws_size,
                              hipStream_t stream) {
  const float* inputs = (const float*)d_in[0];
  const float* h0     = (const float*)d_in[1];
  const float* w_ih   = (const float*)d_in[2];
  const float* w_hh   = (const float*)d_in[3];
  const float* b_ih   = (const float*)d_in[4];
  const float* b_hh   = (const float*)d_in[5];

  float* outBase = (float*)d_out;
  float* hnBase  = outBase + (size_t)BATCH * SEQ * HDIM;

  // ws: hpack ping-pong (2 x 256 KB) + padded flags (16 KB)
  u16* hbuf0 = (u16*)d_ws;
  u16* hbuf1 = hbuf0 + (size_t)NGRP * 32 * 64 * 16;
  int* flags = (int*)(hbuf1 + (size_t)NGRP * 32 * 64 * 16);

  init_kernel<<<256, 256, 0, stream>>>(h0, hbuf0, flags);

  const float* xa = inputs;
  const float* wia = w_ih;
  const float* wha = w_hh;
  const float* bia = b_ih;
  const float* bha = b_hh;
  float* oa = outBase;
  u16 *hb0 = hbuf0, *hb1 = hbuf1;
  int* fa = flags;
  void* args[9] = {&xa, &wia, &wha, &bia, &bha, &oa, &hb0, &hb1, &fa};
  hipLaunchCooperativeKernel((const void*)rnn_fused, dim3(NGRP * BPG), dim3(512), args, 0, stream);

  copy_hn<<<256, 256, 0, stream>>>(outBase, hnBase);
}

// Round 9
// 1618.858 us; speedup vs baseline: 3.5748x; 1.3082x over previous
//
#include <hip/hip_runtime.h>
#include <hip/hip_bf16.h>
#include <stdint.h>

#define BATCH 64
#define SEQ   512
#define INDIM 1024
#define HDIM  1024
#define NBLK  256
#define NGRP  8      // 8 groups x 8 batch rows
#define GSLOT 32     // blocks per group, 32 hidden cols each
#define FPAD  16     // 64 B per flag
#define HELEMS 32768 // u16 per (group, ping-pong buf): 32 k32 x 64 x 16

typedef short bf16x8 __attribute__((ext_vector_type(8)));
typedef short s16x4  __attribute__((ext_vector_type(4)));
typedef float f32x4  __attribute__((ext_vector_type(4)));
typedef unsigned short u16;
typedef unsigned int   u32;
typedef u32 u32x2 __attribute__((ext_vector_type(2)));
typedef u32 u32x4 __attribute__((ext_vector_type(4)));
typedef u16 u16x4 __attribute__((ext_vector_type(4)));

static __device__ __forceinline__ u16 f2bf(float x) {
  unsigned int u = __float_as_uint(x);
  u += 0x7fffu + ((u >> 16) & 1u);
  return (u16)(u >> 16);
}
static __device__ __forceinline__ float bf2f(u16 b) {
  return __uint_as_float(((unsigned int)b) << 16);
}

// device-coherent (LLC-scope) scalar load — the PROVEN sync primitive (r2/r4/r6)
static __device__ __forceinline__ int coh_ld_i32(const int* p) {
  int v;
  asm volatile("global_load_dword %0, %1, off sc0 sc1\n\t"
               "s_waitcnt vmcnt(0)"
               : "=&v"(v) : "v"(p) : "memory");
  return v;
}

static __device__ __forceinline__ void split4(float4 v, u16x4& hi, u16x4& lo) {
  hi.x = f2bf(v.x); lo.x = f2bf(v.x - bf2f(hi.x));
  hi.y = f2bf(v.y); lo.y = f2bf(v.y - bf2f(hi.y));
  hi.z = f2bf(v.z); lo.z = f2bf(v.z - bf2f(hi.z));
  hi.w = f2bf(v.w); lo.w = f2bf(v.w - bf2f(hi.w));
}
// 16B logical read from 8B-aligned LDS row (stride 24B) as two 8B reads
static __device__ __forceinline__ bf16x8 ld8(const u16* p) {
  s16x4 a = *(const s16x4*)p;
  s16x4 b = *(const s16x4*)(p + 4);
  return __builtin_shufflevector(a, b, 0, 1, 2, 3, 4, 5, 6, 7);
}

// ---- init0: zero h buffers + flags ----
__global__ void init0(u32* __restrict__ ws, int n) {
  int i = blockIdx.x * blockDim.x + threadIdx.x;
  if (i < n) ws[i] = 0;
}

// ---- init1: pack h0 into per-group fragment-major hi|lo layout ----
// group g = rows [8g, 8g+8). slot [(k32*4+kg)*16 + r]*16 u16 (8 hi | 8 lo),
// holds h[8g + r][k32*32 + kg*8 + j]; tile rows 8..15 stay zero (init0).
__global__ void init1(const float* __restrict__ h0, u16* __restrict__ hbase) {
  int i = blockIdx.x * blockDim.x + threadIdx.x;
  if (i < BATCH * HDIM) {
    int b = i >> 10, k = i & 1023;
    int g = b >> 3, r = b & 7;
    int k32 = k >> 5, kg = (k >> 3) & 3, j = k & 7;
    float x = h0[i];
    u16 h = f2bf(x);
    size_t u = (size_t)(g * 2) * HELEMS + ((size_t)(k32 * 4 + kg) * 16 + r) * 16 + j;
    hbase[u] = h;
    hbase[u + 8] = f2bf(x - bf2f(h));
  }
}

// ---- xproj: xp = X @ Wih^T + bih + bhh via split-bf16 MFMA (into out) ----
__global__ __launch_bounds__(256) void xproj_kernel(const float* __restrict__ A,
                                                    const float* __restrict__ W,
                                                    const float* __restrict__ bih,
                                                    const float* __restrict__ bhh,
                                                    float* __restrict__ C) {
  __shared__ u16 Ah[4][128][12], Al[4][128][12], Bh[4][128][12], Bl[4][128][12];
  const int nb = blockIdx.x;
  const int mb = blockIdx.y;
  const int m_base = mb * 128, n_base = nb * 128;
  const int tid = (int)threadIdx.x;
  const int wid = tid >> 6, lane = tid & 63;
  const int wm = wid >> 1, wn = wid & 1;
  const int r = lane & 15, kg = lane >> 4;
  const int srow = tid >> 1;
  const int skq  = (tid & 1) * 16;

  const float* ap0 = A + (size_t)(m_base + srow) * INDIM + skq;
  const float* bp0 = W + (size_t)(n_base + srow) * INDIM + skq;

  f32x4 acc[4][4] = {};

  for (int k0 = 0; k0 < INDIM; k0 += 32) {
    float4 av[4], bv[4];
#pragma unroll
    for (int i = 0; i < 4; ++i) {
      av[i] = *(const float4*)(ap0 + k0 + i * 4);
      bv[i] = *(const float4*)(bp0 + k0 + i * 4);
    }
    __syncthreads();
#pragma unroll
    for (int i = 0; i < 4; ++i) {
      int kk = skq + i * 4;
      int kgw = kk >> 3, off = kk & 7;
      u16x4 hi, lo;
      split4(av[i], hi, lo);
      *(u16x4*)&Ah[kgw][srow][off] = hi;
      *(u16x4*)&Al[kgw][srow][off] = lo;
      split4(bv[i], hi, lo);
      *(u16x4*)&Bh[kgw][srow][off] = hi;
      *(u16x4*)&Bl[kgw][srow][off] = lo;
    }
    __syncthreads();

    bf16x8 ah[4], al[4], bhv[4], blv[4];
#pragma unroll
    for (int mf = 0; mf < 4; ++mf) {
      int row = wm * 64 + mf * 16 + r;
      ah[mf] = ld8(&Ah[kg][row][0]);
      al[mf] = ld8(&Al[kg][row][0]);
    }
#pragma unroll
    for (int nf = 0; nf < 4; ++nf) {
      int row = wn * 64 + nf * 16 + r;
      bhv[nf] = ld8(&Bh[kg][row][0]);
      blv[nf] = ld8(&Bl[kg][row][0]);
    }
#pragma unroll
    for (int mf = 0; mf < 4; ++mf)
#pragma unroll
      for (int nf = 0; nf < 4; ++nf) {
        acc[mf][nf] = __builtin_amdgcn_mfma_f32_16x16x32_bf16(ah[mf], bhv[nf], acc[mf][nf], 0, 0, 0);
        acc[mf][nf] = __builtin_amdgcn_mfma_f32_16x16x32_bf16(ah[mf], blv[nf], acc[mf][nf], 0, 0, 0);
        acc[mf][nf] = __builtin_amdgcn_mfma_f32_16x16x32_bf16(al[mf], bhv[nf], acc[mf][nf], 0, 0, 0);
      }
  }

#pragma unroll
  for (int nf = 0; nf < 4; ++nf) {
    int col = n_base + wn * 64 + nf * 16 + r;
    float bias = bih[col] + bhh[col];
#pragma unroll
    for (int mf = 0; mf < 4; ++mf) {
      int rowb = m_base + wm * 64 + mf * 16 + kg * 4;
#pragma unroll
      for (int q = 0; q < 4; ++q) {
        C[(size_t)(rowb + q) * HDIM + col] = acc[mf][nf][q] + bias;
      }
    }
  }
}

// ---- scan: persistent, LLC-scope sync, per-wave producer-only polling ----
// Block b: grp = b&7 (batch rows [8g,8g+8)), slot = b>>3 (cols [32s,32s+32)).
// Wave wv consumes K in [wv*128, wv*128+128) -> polls ONLY slots 4wv..4wv+3.
// One __syncthreads per step. Ping-pong depth 2 (safety proof in journal).
__global__ __launch_bounds__(512, 1) void rnn_scan(
    const float* __restrict__ Whh, float* __restrict__ out,
    u16* hbase, int* flags) {
  __shared__ u16 WH[32][2][64][8], WL[32][2][64][8];   // 128 KB
  __shared__ __align__(16) float red[2][8][2][8][20];  // 20 KB, dbuf, padded

  const int blk = (int)blockIdx.x;
  const int grp = blk & 7;
  const int slot = blk >> 3;
  const int n0 = slot * 32;
  const int tid = (int)threadIdx.x;
  const int wv = tid >> 6, lane = tid & 63;
  const int r = lane & 15, kg = lane >> 4;

  // ---- one-time: stage Whh rows n0..n0+31 into LDS, fragment-major, hi/lo ----
  for (int it = 0; it < 16; ++it) {
    int f4 = it * 512 + tid;            // float4 index in 32x1024 slice
    int row = f4 >> 8;                  // 0..31
    int k0 = (f4 & 255) * 4;
    float4 v = *(const float4*)(Whh + (size_t)(n0 + row) * HDIM + k0);
    int k32 = k0 >> 5, kgg = (k0 >> 3) & 3, j = k0 & 7;
    int nt = row >> 4, ln = kgg * 16 + (row & 15);
    u16x4 hi, lo;
    split4(v, hi, lo);
    *(u16x4*)&WH[k32][nt][ln][j] = hi;
    *(u16x4*)&WL[k32][nt][ln][j] = lo;
  }
  __syncthreads();

  u16* const hb[2] = {hbase + (size_t)(grp * 2) * HELEMS,
                      hbase + (size_t)(grp * 2 + 1) * HELEMS};
  int* const gflag = flags + grp * GSLOT * FPAD;
  const bool zrow = (lane & 15) >= 8;   // A-tile rows 8..15 are structurally zero
  const int* const pollp = gflag + (wv * 4 + (lane & 3)) * FPAD;  // my 4 producers

  // epilogue geometry (wave 0): lane -> (row 0..7, col-quad 0..7)
  const int erow = lane >> 3;
  const int ec = lane & 7;
  const float* xp0 = out + ((size_t)(grp * 8 + erow) * SEQ) * HDIM + n0 + ec * 4;
  float4 xf;
  if (wv == 0) xf = *(const float4*)xp0;   // xp(t=0)

  for (int t = 0; t < SEQ; ++t) {
    const int p = t & 1;
    const u16* hc = hb[p];        // h(t)
    u16* hn = hb[p ^ 1];          // h(t+1)

    // (a) per-wave poll: need h(t) of cols [wv*128, wv*128+128) = slots 4wv..4wv+3
    if (t > 0) {
      int v;
      do { v = coh_ld_i32(pollp); } while (!__all(v >= t));
    }

    // (b) A-fragments: 8 x 16B LLC loads; zero-row lanes synthesize zeros
    u32x4 hh[4], hl[4];
    if (!zrow) {
      const char* a0 = (const char*)hc + ((size_t)(wv * 4) * 64 + lane) * 32;
      const char* a1 = a0 + 4096;
      asm volatile(
          "global_load_dwordx4 %0, %8, off sc0 sc1\n\t"
          "global_load_dwordx4 %1, %8, off offset:16 sc0 sc1\n\t"
          "global_load_dwordx4 %2, %8, off offset:2048 sc0 sc1\n\t"
          "global_load_dwordx4 %3, %8, off offset:2064 sc0 sc1\n\t"
          "global_load_dwordx4 %4, %9, off sc0 sc1\n\t"
          "global_load_dwordx4 %5, %9, off offset:16 sc0 sc1\n\t"
          "global_load_dwordx4 %6, %9, off offset:2048 sc0 sc1\n\t"
          "global_load_dwordx4 %7, %9, off offset:2064 sc0 sc1"
          : "=&v"(hh[0]), "=&v"(hl[0]), "=&v"(hh[1]), "=&v"(hl[1]),
            "=&v"(hh[2]), "=&v"(hl[2]), "=&v"(hh[3]), "=&v"(hl[3])
          : "v"(a0), "v"(a1)
          : "memory");
      asm volatile("s_waitcnt vmcnt(0)"
          : "+v"(hh[0]), "+v"(hl[0]), "+v"(hh[1]), "+v"(hl[1]),
            "+v"(hh[2]), "+v"(hl[2]), "+v"(hh[3]), "+v"(hl[3]));
    } else {
#pragma unroll
      for (int i = 0; i < 4; ++i) { hh[i] = (u32x4){0,0,0,0}; hl[i] = (u32x4){0,0,0,0}; }
    }

    f32x4 acc0 = {0.f, 0.f, 0.f, 0.f};
    f32x4 acc1 = {0.f, 0.f, 0.f, 0.f};
#pragma unroll
    for (int i = 0; i < 4; ++i) {
      int k32 = wv * 4 + i;
      bf16x8 ah = __builtin_bit_cast(bf16x8, hh[i]);
      bf16x8 al = __builtin_bit_cast(bf16x8, hl[i]);
      bf16x8 b0h = *(const bf16x8*)&WH[k32][0][lane][0];
      bf16x8 b0l = *(const bf16x8*)&WL[k32][0][lane][0];
      bf16x8 b1h = *(const bf16x8*)&WH[k32][1][lane][0];
      bf16x8 b1l = *(const bf16x8*)&WL[k32][1][lane][0];
      acc0 = __builtin_amdgcn_mfma_f32_16x16x32_bf16(ah, b0h, acc0, 0, 0, 0);
      acc0 = __builtin_amdgcn_mfma_f32_16x16x32_bf16(ah, b0l, acc0, 0, 0, 0);
      acc0 = __builtin_amdgcn_mfma_f32_16x16x32_bf16(al, b0h, acc0, 0, 0, 0);
      acc1 = __builtin_amdgcn_mfma_f32_16x16x32_bf16(ah, b1h, acc1, 0, 0, 0);
      acc1 = __builtin_amdgcn_mfma_f32_16x16x32_bf16(ah, b1l, acc1, 0, 0, 0);
      acc1 = __builtin_amdgcn_mfma_f32_16x16x32_bf16(al, b1h, acc1, 0, 0, 0);
    }

    // (c) K-reduction scratch. D layout: col = lane&15, row = kg*4+q (rows<8 only)
    if (kg < 2) {
#pragma unroll
      for (int q = 0; q < 4; ++q) {
        red[p][wv][0][kg * 4 + q][r] = acc0[q];
        red[p][wv][1][kg * 4 + q][r] = acc1[q];
      }
    }
    __syncthreads();   // the ONE barrier per step

    if (wv == 0) {
      // (d) epilogue: reduce 8 waves + xp, relu, pack hi/lo, store h, flag, out
      f32x4 s = {xf.x, xf.y, xf.z, xf.w};
      int nt = ec >> 2, cl = (ec & 3) * 4;
#pragma unroll
      for (int w = 0; w < 8; ++w) s += *(const f32x4*)&red[p][w][nt][erow][cl];
#pragma unroll
      for (int j = 0; j < 4; ++j) s[j] = s[j] > 0.f ? s[j] : 0.f;

      union { u16 u[4]; u32x2 d; } HH, LL;
#pragma unroll
      for (int j = 0; j < 4; ++j) {
        u16 h = f2bf(s[j]);
        HH.u[j] = h;
        LL.u[j] = f2bf(s[j] - bf2f(h));
      }
      char* hp = (char*)hn + ((size_t)(slot * 64 + (ec >> 1) * 16 + erow) * 32) + (ec & 1) * 8;
      asm volatile(
          "global_store_dwordx2 %0, %1, off sc0 sc1\n\t"
          "global_store_dwordx2 %0, %2, off offset:16 sc0 sc1\n\t"
          "s_waitcnt vmcnt(0)"
          :: "v"(hp), "v"(HH.d), "v"(LL.d)
          : "memory");
      if (lane == 0) {
        int* fp = gflag + slot * FPAD;
        int tv = t + 1;
        asm volatile("global_store_dword %0, %1, off sc0 sc1"
                     :: "v"(fp), "v"(tv) : "memory");
      }
      // outputs (off critical path, after flag)
      __builtin_nontemporal_store(s,
          (f32x4*)(out + ((size_t)(grp * 8 + erow) * SEQ + t) * HDIM + n0 + ec * 4));
      // prefetch xp(t+1)
      if (t + 1 < SEQ) xf = *(const float4*)(xp0 + (size_t)(t + 1) * HDIM);
    }
  }
}

// ---- h_n = outputs[:, SEQ-1, :] ----
__global__ void copy_hn(const float* __restrict__ out, float* __restrict__ hn) {
  int idx = blockIdx.x * blockDim.x + threadIdx.x;
  if (idx < BATCH * HDIM) {
    int b = idx >> 10, j = idx & 1023;
    hn[idx] = out[((size_t)b * SEQ + (SEQ - 1)) * (size_t)HDIM + j];
  }
}

extern "C" void kernel_launch(void* const* d_in, const int* in_sizes, int n_in,
                              void* d_out, int out_size, void* d_ws, size_t ws_size,
                              hipStream_t stream) {
  const float* inputs = (const float*)d_in[0];
  const float* h0     = (const float*)d_in[1];
  const float* w_ih   = (const float*)d_in[2];
  const float* w_hh   = (const float*)d_in[3];
  const float* b_ih   = (const float*)d_in[4];
  const float* b_hh   = (const float*)d_in[5];

  float* outBase = (float*)d_out;
  float* hnBase  = outBase + (size_t)BATCH * SEQ * HDIM;

  // ws: hbase (8 grp x 2 bufs x 64 KB = 1 MB) | flags 16 KB
  u16* hbase = (u16*)d_ws;
  int* flags = (int*)(hbase + (size_t)NGRP * 2 * HELEMS);
  const int zero_u32 = (int)(((size_t)NGRP * 2 * HELEMS * 2) / 4 + NGRP * GSLOT * FPAD);

  init0<<<(zero_u32 + 255) / 256, 256, 0, stream>>>((u32*)d_ws, zero_u32);
  init1<<<(BATCH * HDIM + 255) / 256, 256, 0, stream>>>(h0, hbase);

  xproj_kernel<<<dim3(8, 256), 256, 0, stream>>>(inputs, w_ih, b_ih, b_hh, outBase);

  const float* wha = w_hh;
  float* oa = outBase;
  u16* hba = hbase;
  int* fa = flags;
  void* args[4] = {&wha, &oa, &hba, &fa};
  (void)hipLaunchCooperativeKernel((const void*)rnn_scan, dim3(NBLK), dim3(512), args, 0, stream);

  copy_hn<<<256, 256, 0, stream>>>(outBase, hnBase);
}